// Round 3
// baseline (2478.952 us; speedup 1.0000x reference)
//
#include <hip/hip_runtime.h>
#include <hip/hip_cooperative_groups.h>
#include <math.h>

namespace cg = cooperative_groups;

typedef unsigned short u16;
typedef unsigned int   u32;
typedef unsigned long long u64;

#define BSZ     16
#define CCH     256
#define TT      768
#define PT      12
#define NPATCHN 64
#define FFD     256
#define NH      4
#define GRID    (BSZ*PT)   /* 192 blocks, one per (b,p) */

/* ---- workspace float offsets ---- */
#define WS_CUR0 0
#define WS_CUR1 49152
#define WS_G1S  98304
#define WS_B1   101376
#define WS_G2S  104448
#define WS_B2   107520
#define WS_WAGG 110592
#define WS_BAGG 110736
#define WS_A    110748
#define WS_CCF  110752
#define WS_M    110756
#define WS_CM1  111780
#define WS_WM2  112036
#define WS_BM2  112292

#define INVSF   0.9999950000374996f   /* 1/sqrt(1+1e-5) */

__device__ __forceinline__ u64 umax64(u64 a, u64 b){ return a > b ? a : b; }

__device__ __forceinline__ float gelu_exact(float v){
  return 0.5f * v * (1.0f + erff(v * 0.7071067811865475f));
}

/* erf(v/sqrt2) = v*R(v^2), Taylor deg-6 in t=v^2, |v|<=1 -> abs err < 1e-7 */
__device__ __forceinline__ float gelu_fast(float v){
  float av = fabsf(v);
  if (__builtin_expect(av > 1.0f, 0))
    return 0.5f * v * (1.0f + erff(v * 0.7071067811865475f));
  float t = v * v;
  float r = 1.3319545e-06f;
  r = fmaf(r, t, -1.8889312e-05f);
  r = fmaf(r, t,  2.3086939e-04f);
  r = fmaf(r, t, -2.3746564e-03f);
  r = fmaf(r, t,  1.9947114e-02f);
  r = fmaf(r, t, -1.3298076e-01f);
  r = fmaf(r, t,  7.9788456e-01f);
  float a = 0.5f * v;
  return fmaf(a * v, r, a);   /* 0.5v + 0.5v*(v*R) */
}

/* ------------ precompute: fold rank-1 structure into small tables ------------ */
__global__ __launch_bounds__(1024) void precompute_kernel(
    const float* __restrict__ gg1, const float* __restrict__ bb1,
    const float* __restrict__ gg2, const float* __restrict__ bb2,
    const float* __restrict__ Wagg, const float* __restrict__ bagg,
    const float* __restrict__ We,  const float* __restrict__ be,
    const float* __restrict__ Wq,  const float* __restrict__ bq,
    const float* __restrict__ Wk,  const float* __restrict__ bk,
    const float* __restrict__ Wv,  const float* __restrict__ bv,
    const float* __restrict__ Wm1, const float* __restrict__ bm1,
    const float* __restrict__ Wm2, const float* __restrict__ bm2,
    float* __restrict__ ws)
{
  __shared__ float We_s[FFD], be_s[FFD];
  __shared__ float wq_s[FFD], cq_s[FFD], wk_s[FFD], ck_s[FFD], wv_s[FFD], cv_s[FFD];
  const int tid  = threadIdx.x;
  const int lane = tid & 63;
  const int w    = tid >> 6;   /* 16 waves */

  if (tid < FFD) { We_s[tid] = We[tid]; be_s[tid] = be[tid]; }
  __syncthreads();

  /* wave-per-row matvecs: wq = Wq@We, cq = Wq@be + bq, etc. (coalesced) */
  for (int f = w; f < FFD; f += 16) {
    float aq=0.f, cqa=0.f, ak=0.f, cka=0.f, av=0.f, cva=0.f;
    #pragma unroll
    for (int k2 = 0; k2 < 4; ++k2) {
      int j = lane + 64*k2;
      float wev = We_s[j], bev = be_s[j];
      float q1 = Wq[f*FFD + j]; aq += q1*wev; cqa += q1*bev;
      float k1 = Wk[f*FFD + j]; ak += k1*wev; cka += k1*bev;
      float v1 = Wv[f*FFD + j]; av += v1*wev; cva += v1*bev;
    }
    for (int ofs = 1; ofs < 64; ofs <<= 1) {
      aq += __shfl_xor(aq, ofs);  cqa += __shfl_xor(cqa, ofs);
      ak += __shfl_xor(ak, ofs);  cka += __shfl_xor(cka, ofs);
      av += __shfl_xor(av, ofs);  cva += __shfl_xor(cva, ofs);
    }
    if (lane == 0) {
      wq_s[f] = aq; cq_s[f] = cqa + bq[f];
      wk_s[f] = ak; ck_s[f] = cka + bk[f];
      wv_s[f] = av; cv_s[f] = cva + bv[f];
    }
  }
  __syncthreads();

  /* per-head A = <wq,wk>/8, C = <cq,wk>/8 (coef of s_e; beta cancels in softmax) */
  if (w < NH) {
    int f = w*64 + lane;
    float a  = wq_s[f]*wk_s[f];
    float cc = cq_s[f]*wk_s[f];
    for (int ofs = 1; ofs < 64; ofs <<= 1) { a += __shfl_xor(a, ofs); cc += __shfl_xor(cc, ofs); }
    if (lane == 0) { ws[WS_A + w] = a * 0.125f; ws[WS_CCF + w] = cc * 0.125f; }
  }

  /* M[g,h] = sum_{f in head h} Wm1[g,f]*wv[f]; cm1[g] = Wm1@cv + bm1 */
  for (int g = w; g < FFD; g += 16) {
    float mk0=0.f, mk1=0.f, mk2=0.f, mk3=0.f, ca=0.f;
    #pragma unroll
    for (int k2 = 0; k2 < 4; ++k2) {
      int j = lane + 64*k2;
      float wv1 = Wm1[g*FFD + j];
      float pm = wv1 * wv_s[j];
      if (k2 == 0) mk0 = pm; else if (k2 == 1) mk1 = pm; else if (k2 == 2) mk2 = pm; else mk3 = pm;
      ca += wv1 * cv_s[j];
    }
    for (int ofs = 1; ofs < 64; ofs <<= 1) {
      mk0 += __shfl_xor(mk0, ofs); mk1 += __shfl_xor(mk1, ofs);
      mk2 += __shfl_xor(mk2, ofs); mk3 += __shfl_xor(mk3, ofs);
      ca  += __shfl_xor(ca,  ofs);
    }
    if (lane == 0) {
      ws[WS_M + g*4 + 0] = mk0; ws[WS_M + g*4 + 1] = mk1;
      ws[WS_M + g*4 + 2] = mk2; ws[WS_M + g*4 + 3] = mk3;
      ws[WS_CM1 + g] = ca + bm1[g];
    }
  }

  if (tid < FFD)   ws[WS_WM2 + tid] = Wm2[tid];
  if (tid == 0)    ws[WS_BM2] = bm2[0];
  if (tid < PT*PT) ws[WS_WAGG + tid] = Wagg[tid];
  if (tid < PT)    ws[WS_BAGG + tid] = bagg[tid];
  for (int i = tid; i < CCH*PT; i += 1024) {
    ws[WS_G1S + i] = gg1[i] * INVSF;  ws[WS_B1 + i] = bb1[i];
    ws[WS_G2S + i] = gg2[i] * INVSF;  ws[WS_B2 + i] = bb2[i];
  }
}

/* ------------ main: 63 sequential steps, one grid.sync each ------------ */
__global__ __launch_bounds__(1024) void main_kernel(
    const float* __restrict__ x, const float* __restrict__ g0, const float* __restrict__ b0,
    float* __restrict__ ws, float* __restrict__ out)
{
  cg::grid_group grid = cg::this_grid();
  const int blk = blockIdx.x;
  const int b   = blk / PT;
  const int p   = blk % PT;
  const int tid = threadIdx.x;

  __shared__ float s_sh[CCH];
  __shared__ __align__(16) float S1_sh[CCH*4];
  __shared__ __align__(16) float zpart[16*CCH];
  __shared__ __align__(16) float M_sh[CCH*4];
  __shared__ __align__(8)  float cw_sh[CCH*2];
  __shared__ float g1t_sh[PT*CCH], b1t_sh[PT*CCH];
  __shared__ float g2col_sh[CCH], b2col_sh[CCH];
  __shared__ float wagg_sh[PT];
  __shared__ u64 redbuf[2][4];

  /* preload per-block constants into LDS (transposed BN1 for conflict-free reads) */
  for (int i = tid; i < CCH*PT; i += 1024) {
    int cc = i / PT, jj = i - cc*PT;
    g1t_sh[jj*CCH + cc] = ws[WS_G1S + i];
    b1t_sh[jj*CCH + cc] = ws[WS_B1 + i];
  }
  for (int i = tid; i < CCH*4; i += 1024) M_sh[i] = ws[WS_M + i];
  if (tid < CCH) {
    cw_sh[2*tid]     = ws[WS_CM1 + tid];
    cw_sh[2*tid + 1] = ws[WS_WM2 + tid];
    g2col_sh[tid]    = ws[WS_G2S + tid*PT + p];
    b2col_sh[tid]    = ws[WS_B2  + tid*PT + p];
  }
  if (tid < PT) wagg_sh[tid] = ws[WS_WAGG + p*PT + tid];
  float Ah[NH], Ch[NH];
  #pragma unroll
  for (int h = 0; h < NH; ++h) { Ah[h] = ws[WS_A + h]; Ch[h] = ws[WS_CCF + h]; }
  const float baggp = ws[WS_BAGG + p];
  const float bm2v  = ws[WS_BM2];
  __syncthreads();

  float* cur0 = ws + WS_CUR0;
  float* cur1 = ws + WS_CUR1;

  float res = 0.f;

  /* t = 0: out0 = BN0(x) patch 0 */
  if (tid < CCH) {
    int ict = tid*TT + p;
    float xv = fmaf(x[b*CCH*TT + ict], g0[ict] * INVSF, b0[ict]);
    cur0[(b*CCH + tid)*PT + p] = xv;
    out[b*CCH*TT + tid*TT + p] = xv;
  }
  grid.sync();

  for (int t = 1; t < NPATCHN; ++t) {
    const float* prev = ((t & 1) ? cur0 : cur1);
    float*       next = ((t & 1) ? cur1 : cur0);

    /* ---- phase A: BN1 + agg(12x12) + gelu + residual; s = BN2(res) ---- */
    if (tid < CCH) {
      const float4* pr4 = (const float4*)(prev + (b*CCH + tid)*PT);
      float4 pa = pr4[0], pb = pr4[1], pc4 = pr4[2];
      float pv[12] = {pa.x,pa.y,pa.z,pa.w, pb.x,pb.y,pb.z,pb.w, pc4.x,pc4.y,pc4.z,pc4.w};
      float acc = baggp;
      #pragma unroll
      for (int j = 0; j < PT; ++j)
        acc += fmaf(pv[j], g1t_sh[j*CCH + tid], b1t_sh[j*CCH + tid]) * wagg_sh[j];
      float inp = gelu_exact(acc);
      int ict = tid*TT + t*PT + p;
      float xv = fmaf(x[b*CCH*TT + ict], g0[ict] * INVSF, b0[ict]);
      res = inp + xv;
      s_sh[tid] = fmaf(res, g2col_sh[tid], b2col_sh[tid]);
    }
    __syncthreads();

    /* ---- phase B: top-3 / bottom-3 of s over channels (tie -> lowest idx) ---- */
    const int cb  = tid & (CCH-1);
    const int grp = tid >> 8;
    u64 key = 0;
    if (grp < 2) {
      u32 u = __float_as_uint(s_sh[cb]);
      u32 srt = (u & 0x80000000u) ? ~u : (u | 0x80000000u);
      if (grp == 1) srt = ~srt;               /* group1: bottom-3 */
      key = (((u64)srt) << 32) | (u64)(u32)(CCH - 1 - cb);
    }
    float tv[3], bvv[3];
    #pragma unroll
    for (int r = 0; r < 3; ++r) {
      if (grp < 2) {
        u64 k = key;
        #pragma unroll
        for (int ofs = 1; ofs < 64; ofs <<= 1) k = umax64(k, __shfl_xor(k, ofs));
        if ((tid & 63) == 0) redbuf[grp][(tid >> 6) & 3] = k;
      }
      __syncthreads();
      u64 w0 = umax64(umax64(redbuf[0][0], redbuf[0][1]), umax64(redbuf[0][2], redbuf[0][3]));
      u64 w1 = umax64(umax64(redbuf[1][0], redbuf[1][1]), umax64(redbuf[1][2], redbuf[1][3]));
      int ti_ = CCH - 1 - (int)(u32)(w0 & 0xffffffffu);
      int bi_ = CCH - 1 - (int)(u32)(w1 & 0xffffffffu);
      tv[r]  = s_sh[ti_];
      bvv[r] = s_sh[bi_];
      if (grp == 0 && cb == ti_) key = 0;
      if (grp == 1 && cb == bi_) key = 0;
      __syncthreads();
    }

    /* ---- phase C: S1[h] per channel (softmax over 3 selected scalars) ---- */
    if (tid < CCH) {
      float sval = s_sh[tid];
      float S1v[NH];
      #pragma unroll
      for (int h = 0; h < NH; ++h) {
        float alpha = fmaf(Ah[h], sval, Ch[h]);
        bool pos = alpha > 0.0f;
        float v1 = pos ? tv[0] : bvv[0];
        float v2 = pos ? tv[1] : bvv[1];
        float v3 = pos ? tv[2] : bvv[2];
        float m  = alpha * v1;
        float e2 = __expf(alpha * v2 - m);
        float e3 = __expf(alpha * v3 - m);
        float num = fmaf(e2, v2, v1) + e3 * v3;
        float den = (1.0f + e2) + e3;
        float s1 = num / den;
        if (alpha == 0.0f) s1 = (s_sh[0] + s_sh[1] + s_sh[2]) * (1.0f/3.0f);
        S1v[h] = s1;
      }
      *(float4*)&S1_sh[tid*4] = make_float4(S1v[0], S1v[1], S1v[2], S1v[3]);
    }
    __syncthreads();

    /* ---- phase C2: z = sum_g Wm2[g]*gelu(M[g,:]@S1 + cm1[g]); 4 channels/thread ---- */
    {
      const int quad = tid & 63;
      const int qq   = tid >> 6;      /* 16 g-groups of 16 */
      const int c0   = quad * 4;
      const float4 s10 = *(const float4*)&S1_sh[(c0+0)*4];
      const float4 s11 = *(const float4*)&S1_sh[(c0+1)*4];
      const float4 s12 = *(const float4*)&S1_sh[(c0+2)*4];
      const float4 s13 = *(const float4*)&S1_sh[(c0+3)*4];
      float a0=0.f, a1=0.f, a2=0.f, a3=0.f;
      const int gb = qq * 16;
      #pragma unroll 4
      for (int g = 0; g < 16; ++g) {
        const float4 m4 = *(const float4*)&M_sh[(gb + g)*4];
        const float2 cw = *(const float2*)&cw_sh[(gb + g)*2];
        float u0 = fmaf(m4.x, s10.x, cw.x); u0 = fmaf(m4.y, s10.y, u0); u0 = fmaf(m4.z, s10.z, u0); u0 = fmaf(m4.w, s10.w, u0);
        float u1 = fmaf(m4.x, s11.x, cw.x); u1 = fmaf(m4.y, s11.y, u1); u1 = fmaf(m4.z, s11.z, u1); u1 = fmaf(m4.w, s11.w, u1);
        float u2 = fmaf(m4.x, s12.x, cw.x); u2 = fmaf(m4.y, s12.y, u2); u2 = fmaf(m4.z, s12.z, u2); u2 = fmaf(m4.w, s12.w, u2);
        float u3 = fmaf(m4.x, s13.x, cw.x); u3 = fmaf(m4.y, s13.y, u3); u3 = fmaf(m4.z, s13.z, u3); u3 = fmaf(m4.w, s13.w, u3);
        a0 = fmaf(cw.y, gelu_fast(u0), a0);
        a1 = fmaf(cw.y, gelu_fast(u1), a1);
        a2 = fmaf(cw.y, gelu_fast(u2), a2);
        a3 = fmaf(cw.y, gelu_fast(u3), a3);
      }
      *(float4*)&zpart[qq*CCH + c0] = make_float4(a0, a1, a2, a3);
    }
    __syncthreads();

    /* ---- phase D: reduce partials, new = res + 0.5*z, write state + output ---- */
    if (tid < CCH) {
      float z = 0.f;
      #pragma unroll
      for (int qq = 0; qq < 16; ++qq) z += zpart[qq*CCH + tid];
      z += bm2v;
      float nw = fmaf(0.5f, z, res);
      next[(b*CCH + tid)*PT + p] = nw;
      out[b*CCH*TT + tid*TT + t*PT + p] = nw;
    }
    grid.sync();
  }
}

extern "C" void kernel_launch(void* const* d_in, const int* in_sizes, int n_in,
                              void* d_out, int out_size, void* d_ws, size_t ws_size,
                              hipStream_t stream) {
  (void)in_sizes; (void)n_in; (void)out_size; (void)ws_size;
  const float* x    = (const float*)d_in[0];
  const float* g0   = (const float*)d_in[1];
  const float* b0   = (const float*)d_in[2];
  const float* gg1  = (const float*)d_in[3];
  const float* bb1  = (const float*)d_in[4];
  const float* gg2  = (const float*)d_in[5];
  const float* bb2  = (const float*)d_in[6];
  const float* Wagg = (const float*)d_in[7];
  const float* bagg = (const float*)d_in[8];
  const float* We   = (const float*)d_in[9];
  const float* be   = (const float*)d_in[10];
  const float* Wq   = (const float*)d_in[11];
  const float* bq   = (const float*)d_in[12];
  const float* Wk   = (const float*)d_in[13];
  const float* bk   = (const float*)d_in[14];
  const float* Wv   = (const float*)d_in[15];
  const float* bv   = (const float*)d_in[16];
  const float* Wm1  = (const float*)d_in[17];
  const float* bm1  = (const float*)d_in[18];
  const float* Wm2  = (const float*)d_in[19];
  const float* bm2  = (const float*)d_in[20];
  float* ws  = (float*)d_ws;
  float* out = (float*)d_out;

  hipLaunchKernelGGL(precompute_kernel, dim3(1), dim3(1024), 0, stream,
                     gg1, bb1, gg2, bb2, Wagg, bagg, We, be,
                     Wq, bq, Wk, bk, Wv, bv, Wm1, bm1, Wm2, bm2, ws);

  void* kargs[] = { (void*)&x, (void*)&g0, (void*)&b0, (void*)&ws, (void*)&out };
  hipLaunchCooperativeKernel(main_kernel, dim3(GRID), dim3(1024), kargs, 0, stream);
}

// Round 4
// 908.532 us; speedup vs baseline: 2.7285x; 2.7285x over previous
//
#include <hip/hip_runtime.h>
#include <hip/hip_cooperative_groups.h>
#include <math.h>

namespace cg = cooperative_groups;

typedef unsigned int   u32;
typedef unsigned long long u64;

#define BSZ     16
#define CCH     256
#define TT      768
#define PT      12
#define NPATCHN 64
#define FFD     256
#define NH      4
#define GRID    (BSZ*PT)   /* 192 blocks; blk = p*16 + b  (12 blocks of b share an XCD) */

/* ---- workspace float offsets ---- */
#define WS_ST0  0
#define WS_ST1  49152
#define WS_G1S  98304
#define WS_B1   101376
#define WS_G2S  104448
#define WS_B2   107520
#define WS_WAGG 110592
#define WS_BAGG 110736
#define WS_A    110748
#define WS_CCF  110752
#define WS_M    110756
#define WS_CM1  111780
#define WS_WM2  112036
#define WS_BM2  112292
#define WS_BAR  112320                      /* int[16*64], 256B-spaced counters */
#define WS_XT   113408                      /* [16][768][256] BN0-folded x, transposed */
#define WS_OB   (113408 + BSZ*TT*CCH)       /* [16][768][256] out buffer (t-major) */
#define WS_END  (WS_OB + BSZ*TT*CCH)

#define INVSF   0.9999950000374996f   /* 1/sqrt(1+1e-5) */

__device__ __forceinline__ float med3f(float a, float b, float c){
  return fmaxf(fminf(a,b), fminf(fmaxf(a,b), c));
}

__device__ __forceinline__ float gelu_exact(float v){
  return 0.5f * v * (1.0f + erff(v * 0.7071067811865475f));
}

/* erf(v/sqrt2) = v*R(v^2), Taylor deg-6 in t=v^2, |v|<=1 -> abs err < 1e-7 */
__device__ __forceinline__ float gelu_fast(float v){
  float av = fabsf(v);
  if (__builtin_expect(av > 1.0f, 0))
    return 0.5f * v * (1.0f + erff(v * 0.7071067811865475f));
  float t = v * v;
  float r = 1.3319545e-06f;
  r = fmaf(r, t, -1.8889312e-05f);
  r = fmaf(r, t,  2.3086939e-04f);
  r = fmaf(r, t, -2.3746564e-03f);
  r = fmaf(r, t,  1.9947114e-02f);
  r = fmaf(r, t, -1.3298076e-01f);
  r = fmaf(r, t,  7.9788456e-01f);
  float a = 0.5f * v;
  return fmaf(a * v, r, a);
}

/* ------------ precompute: fold rank-1 structure into small tables ------------ */
__global__ __launch_bounds__(1024) void precompute_kernel(
    const float* __restrict__ gg1, const float* __restrict__ bb1,
    const float* __restrict__ gg2, const float* __restrict__ bb2,
    const float* __restrict__ Wagg, const float* __restrict__ bagg,
    const float* __restrict__ We,  const float* __restrict__ be,
    const float* __restrict__ Wq,  const float* __restrict__ bq,
    const float* __restrict__ Wk,  const float* __restrict__ bk,
    const float* __restrict__ Wv,  const float* __restrict__ bv,
    const float* __restrict__ Wm1, const float* __restrict__ bm1,
    const float* __restrict__ Wm2, const float* __restrict__ bm2,
    float* __restrict__ ws)
{
  __shared__ float We_s[FFD], be_s[FFD];
  __shared__ float wq_s[FFD], cq_s[FFD], wk_s[FFD], wv_s[FFD], cv_s[FFD];
  const int tid  = threadIdx.x;
  const int lane = tid & 63;
  const int w    = tid >> 6;   /* 16 waves */

  if (tid < FFD) { We_s[tid] = We[tid]; be_s[tid] = be[tid]; }
  /* zero the per-b barrier counters (ws is poisoned before every launch) */
  if (tid < 16*64) ((int*)(ws + WS_BAR))[tid] = 0;
  __syncthreads();

  for (int f = w; f < FFD; f += 16) {
    float aq=0.f, cqa=0.f, ak=0.f, av=0.f, cva=0.f;
    #pragma unroll
    for (int k2 = 0; k2 < 4; ++k2) {
      int j = lane + 64*k2;
      float wev = We_s[j], bev = be_s[j];
      float q1 = Wq[f*FFD + j]; aq += q1*wev; cqa += q1*bev;
      float k1 = Wk[f*FFD + j]; ak += k1*wev;
      float v1 = Wv[f*FFD + j]; av += v1*wev; cva += v1*bev;
    }
    for (int ofs = 1; ofs < 64; ofs <<= 1) {
      aq += __shfl_xor(aq, ofs);  cqa += __shfl_xor(cqa, ofs);
      ak += __shfl_xor(ak, ofs);
      av += __shfl_xor(av, ofs);  cva += __shfl_xor(cva, ofs);
    }
    if (lane == 0) {
      wq_s[f] = aq; cq_s[f] = cqa + bq[f];
      wk_s[f] = ak;
      wv_s[f] = av; cv_s[f] = cva + bv[f];
    }
  }
  __syncthreads();

  if (w < NH) {
    int f = w*64 + lane;
    float a  = wq_s[f]*wk_s[f];
    float cc = cq_s[f]*wk_s[f];
    for (int ofs = 1; ofs < 64; ofs <<= 1) { a += __shfl_xor(a, ofs); cc += __shfl_xor(cc, ofs); }
    if (lane == 0) { ws[WS_A + w] = a * 0.125f; ws[WS_CCF + w] = cc * 0.125f; }
  }

  for (int g = w; g < FFD; g += 16) {
    float mk0=0.f, mk1=0.f, mk2=0.f, mk3=0.f, ca=0.f;
    #pragma unroll
    for (int k2 = 0; k2 < 4; ++k2) {
      int j = lane + 64*k2;
      float wv1 = Wm1[g*FFD + j];
      float pm = wv1 * wv_s[j];
      if (k2 == 0) mk0 = pm; else if (k2 == 1) mk1 = pm; else if (k2 == 2) mk2 = pm; else mk3 = pm;
      ca += wv1 * cv_s[j];
    }
    for (int ofs = 1; ofs < 64; ofs <<= 1) {
      mk0 += __shfl_xor(mk0, ofs); mk1 += __shfl_xor(mk1, ofs);
      mk2 += __shfl_xor(mk2, ofs); mk3 += __shfl_xor(mk3, ofs);
      ca  += __shfl_xor(ca,  ofs);
    }
    if (lane == 0) {
      ws[WS_M + g*4 + 0] = mk0; ws[WS_M + g*4 + 1] = mk1;
      ws[WS_M + g*4 + 2] = mk2; ws[WS_M + g*4 + 3] = mk3;
      ws[WS_CM1 + g] = ca + bm1[g];
    }
  }

  if (tid < FFD)   ws[WS_WM2 + tid] = Wm2[tid];
  if (tid == 0)    ws[WS_BM2] = bm2[0];
  if (tid < PT*PT) ws[WS_WAGG + tid] = Wagg[tid];
  if (tid < PT)    ws[WS_BAGG + tid] = bagg[tid];
  for (int i = tid; i < CCH*PT; i += 1024) {
    ws[WS_G1S + i] = gg1[i] * INVSF;  ws[WS_B1 + i] = bb1[i];
    ws[WS_G2S + i] = gg2[i] * INVSF;  ws[WS_B2 + i] = bb2[i];
  }
}

/* ------ pre: xT[b][t][c] = BN0(x)[b][c][t]  (coalesced 32x32 LDS tiles) ------ */
__global__ __launch_bounds__(256) void pre_transpose(
    const float* __restrict__ x, const float* __restrict__ g0,
    const float* __restrict__ b0, float* __restrict__ ws)
{
  __shared__ float tile[32][33];
  const int b  = blockIdx.z;
  const int c0 = blockIdx.y * 32;
  const int t0 = blockIdx.x * 32;
  const int tx = threadIdx.x & 31;
  const int ty = threadIdx.x >> 5;
  #pragma unroll
  for (int r = 0; r < 4; ++r) {
    int c = c0 + ty + r*8;
    int ict = c*TT + t0 + tx;
    tile[ty + r*8][tx] = fmaf(x[b*CCH*TT + ict], g0[ict]*INVSF, b0[ict]);
  }
  __syncthreads();
  #pragma unroll
  for (int r = 0; r < 4; ++r) {
    int tt = t0 + ty + r*8;
    ws[WS_XT + (b*TT + tt)*CCH + c0 + tx] = tile[tx][ty + r*8];
  }
}

/* ------ post: out[b][c][t] = outbuf[b][t][c] ------ */
__global__ __launch_bounds__(256) void post_transpose(
    const float* __restrict__ ws, float* __restrict__ out)
{
  __shared__ float tile[32][33];
  const int b  = blockIdx.z;
  const int c0 = blockIdx.y * 32;
  const int t0 = blockIdx.x * 32;
  const int tx = threadIdx.x & 31;
  const int ty = threadIdx.x >> 5;
  #pragma unroll
  for (int r = 0; r < 4; ++r) {
    int tt = t0 + ty + r*8;
    tile[ty + r*8][tx] = ws[WS_OB + (b*TT + tt)*CCH + c0 + tx];
  }
  __syncthreads();
  #pragma unroll
  for (int r = 0; r < 4; ++r) {
    int c = c0 + ty + r*8;
    out[b*CCH*TT + c*TT + t0 + tx] = tile[tx][ty + r*8];
  }
}

/* ------------ main: 63 sequential steps, per-b 12-block barrier ------------ */
__global__ __launch_bounds__(1024) void main_kernel(
    const float* __restrict__ x, const float* __restrict__ g0, const float* __restrict__ b0,
    float* __restrict__ ws, float* __restrict__ out, int big)
{
  const int blk = blockIdx.x;
  const int b   = blk & 15;          /* 12 blocks of b land on one XCD (blk%8 = b%8) */
  const int p   = blk >> 4;
  const int tid = threadIdx.x;

  __shared__ float s_sh[CCH];
  __shared__ __align__(16) float S1_sh[NH][CCH];
  __shared__ __align__(16) float zpart[16][CCH];
  __shared__ __align__(16) float apart[4][CCH];
  __shared__ __align__(16) float M_sh[CCH*4];
  __shared__ __align__(8)  float cw_sh[CCH*2];
  __shared__ float g1t_sh[PT][CCH], b1t_sh[PT][CCH];
  __shared__ float g2col_sh[CCH], b2col_sh[CCH];
  __shared__ float wagg_sh[PT];
  __shared__ float tb_sh[8];

  for (int i = tid; i < CCH*PT; i += 1024) {
    int cc = i / PT, jj = i - cc*PT;
    g1t_sh[jj][cc] = ws[WS_G1S + i];
    b1t_sh[jj][cc] = ws[WS_B1 + i];
  }
  for (int i = tid; i < CCH*4; i += 1024) M_sh[i] = ws[WS_M + i];
  if (tid < CCH) {
    cw_sh[2*tid]     = ws[WS_CM1 + tid];
    cw_sh[2*tid + 1] = ws[WS_WM2 + tid];
    g2col_sh[tid]    = ws[WS_G2S + tid*PT + p];
    b2col_sh[tid]    = ws[WS_B2  + tid*PT + p];
  }
  if (tid < PT) wagg_sh[tid] = ws[WS_WAGG + p*PT + tid];
  float Ah[NH], Ch[NH];
  #pragma unroll
  for (int h = 0; h < NH; ++h) { Ah[h] = ws[WS_A + h]; Ch[h] = ws[WS_CCF + h]; }
  const float baggp = ws[WS_BAGG + p];
  const float bm2v  = ws[WS_BM2];
  int* bar = ((int*)(ws + WS_BAR)) + b*64;
  __syncthreads();

  /* t = 0: state[b][p][c] = BN0(x) column p */
  if (tid < CCH) {
    float xv;
    if (big) xv = ws[WS_XT + (b*TT + p)*CCH + tid];
    else { int ict = tid*TT + p; xv = fmaf(x[b*CCH*TT + ict], g0[ict]*INVSF, b0[ict]); }
    ws[WS_ST0 + (b*PT + p)*CCH + tid] = xv;
    if (big) ws[WS_OB + (b*TT + p)*CCH + tid] = xv;
    else     out[b*CCH*TT + tid*TT + p] = xv;
  }
  /* initial exchange barrier (arrival #1 of 63+1 rounds: target 12*t with t0 round = 12) */
  __syncthreads();
  if (tid == 0) {
    __hip_atomic_fetch_add(bar, 1, __ATOMIC_RELEASE, __HIP_MEMORY_SCOPE_AGENT);
    while (__hip_atomic_load(bar, __ATOMIC_RELAXED, __HIP_MEMORY_SCOPE_AGENT) < 12)
      __builtin_amdgcn_s_sleep(1);
    __builtin_amdgcn_fence(__ATOMIC_ACQUIRE, "agent");
  }
  __syncthreads();

  float res = 0.f;

  for (int t = 1; t < NPATCHN; ++t) {
    const float* stP = ws + ((t & 1) ? WS_ST0 : WS_ST1) + (b*PT)*CCH;
    float*       stN = ws + ((t & 1) ? WS_ST1 : WS_ST0) + (b*PT)*CCH;

    /* ---- phase A: BN1 + agg + gelu + residual; s = BN2(res). 16 waves. ---- */
    {
      const int jg = tid >> 8;          /* 0..3, three j each */
      const int c  = tid & 255;
      float part = 0.f;
      #pragma unroll
      for (int k = 0; k < 3; ++k) {
        int j = jg*3 + k;
        part += fmaf(stP[j*CCH + c], g1t_sh[j][c], b1t_sh[j][c]) * wagg_sh[j];
      }
      apart[jg][c] = part;
    }
    __syncthreads();
    if (tid < CCH) {
      float acc = baggp + ((apart[0][tid] + apart[1][tid]) + (apart[2][tid] + apart[3][tid]));
      float inp = gelu_exact(acc);
      float xv;
      if (big) xv = ws[WS_XT + (b*TT + t*PT + p)*CCH + tid];
      else { int ict = tid*TT + t*PT + p; xv = fmaf(x[b*CCH*TT + ict], g0[ict]*INVSF, b0[ict]); }
      res = inp + xv;
      s_sh[tid] = fmaf(res, g2col_sh[tid], b2col_sh[tid]);
    }
    __syncthreads();

    /* ---- phase B: value-only top-3 (wave 0) / bottom-3 (wave 1) ---- */
    {
      const int wv = tid >> 6, lane = tid & 63;
      if (wv < 2) {
        float v0 = s_sh[lane], v1 = s_sh[lane+64], v2 = s_sh[lane+128], v3 = s_sh[lane+192];
        if (wv == 1) { v0 = -v0; v1 = -v1; v2 = -v2; v3 = -v3; }
        float h1 = fmaxf(v0,v1), l1 = fminf(v0,v1);
        float h2 = fmaxf(v2,v3), l2 = fminf(v2,v3);
        float y1 = fminf(h1,h2), x2 = fmaxf(l1,l2);
        float t1 = fmaxf(h1,h2);
        float t2 = fmaxf(y1,x2);
        float t3 = fminf(y1,x2);
        #pragma unroll
        for (int ofs = 1; ofs < 64; ofs <<= 1) {
          float o1 = __shfl_xor(t1, ofs), o2 = __shfl_xor(t2, ofs), o3 = __shfl_xor(t3, ofs);
          float yy = fminf(t1,o1), xx = fmaxf(t2,o2);
          float n1 = fmaxf(t1,o1);
          float n2 = fmaxf(yy,xx);
          float n3 = med3f(yy, xx, fmaxf(t3,o3));
          t1 = n1; t2 = n2; t3 = n3;
        }
        if (lane == 0) {
          if (wv == 0) { tb_sh[0] = t1; tb_sh[1] = t2; tb_sh[2] = t3; }
          else         { tb_sh[4] = -t1; tb_sh[5] = -t2; tb_sh[6] = -t3; }
        }
      }
    }
    __syncthreads();

    /* ---- phase C: per-channel S1[h] (softmax over the 3 selected values) ---- */
    if (tid < CCH) {
      float sval = s_sh[tid];
      float tv0 = tb_sh[0], tv1 = tb_sh[1], tv2 = tb_sh[2];
      float bv0 = tb_sh[4], bv1 = tb_sh[5], bv2 = tb_sh[6];
      #pragma unroll
      for (int h = 0; h < NH; ++h) {
        float alpha = fmaf(Ah[h], sval, Ch[h]);
        bool pos = alpha > 0.0f;
        float v1 = pos ? tv0 : bv0;
        float v2 = pos ? tv1 : bv1;
        float v3 = pos ? tv2 : bv2;
        float m  = alpha * v1;
        float e2 = __expf(fmaf(alpha, v2, -m));
        float e3 = __expf(fmaf(alpha, v3, -m));
        float num = fmaf(e2, v2, v1) + e3 * v3;
        float den = (1.0f + e2) + e3;
        float s1 = num / den;
        if (alpha == 0.0f) s1 = (s_sh[0] + s_sh[1] + s_sh[2]) * (1.0f/3.0f);
        S1_sh[h][tid] = s1;
      }
    }
    __syncthreads();

    /* ---- phase C2: z = sum_g Wm2[g]*gelu(M[g,:]@S1 + cm1[g]); 4 ch/thread ---- */
    {
      const int quad = tid & 63;
      const int qq   = tid >> 6;
      const int c0   = quad * 4;
      const float4 s0 = *(const float4*)&S1_sh[0][c0];
      const float4 s1 = *(const float4*)&S1_sh[1][c0];
      const float4 s2 = *(const float4*)&S1_sh[2][c0];
      const float4 s3 = *(const float4*)&S1_sh[3][c0];
      float a0=0.f, a1=0.f, a2=0.f, a3=0.f;
      const int gb = qq * 16;
      #pragma unroll 4
      for (int g = 0; g < 16; ++g) {
        const float4 m4 = *(const float4*)&M_sh[(gb + g)*4];
        const float2 cw = *(const float2*)&cw_sh[(gb + g)*2];
        float u0 = fmaf(m4.x, s0.x, cw.x); u0 = fmaf(m4.y, s1.x, u0); u0 = fmaf(m4.z, s2.x, u0); u0 = fmaf(m4.w, s3.x, u0);
        float u1 = fmaf(m4.x, s0.y, cw.x); u1 = fmaf(m4.y, s1.y, u1); u1 = fmaf(m4.z, s2.y, u1); u1 = fmaf(m4.w, s3.y, u1);
        float u2 = fmaf(m4.x, s0.z, cw.x); u2 = fmaf(m4.y, s1.z, u2); u2 = fmaf(m4.z, s2.z, u2); u2 = fmaf(m4.w, s3.z, u2);
        float u3 = fmaf(m4.x, s0.w, cw.x); u3 = fmaf(m4.y, s1.w, u3); u3 = fmaf(m4.z, s2.w, u3); u3 = fmaf(m4.w, s3.w, u3);
        a0 = fmaf(cw.y, gelu_fast(u0), a0);
        a1 = fmaf(cw.y, gelu_fast(u1), a1);
        a2 = fmaf(cw.y, gelu_fast(u2), a2);
        a3 = fmaf(cw.y, gelu_fast(u3), a3);
      }
      *(float4*)&zpart[qq][c0] = make_float4(a0, a1, a2, a3);
    }
    __syncthreads();

    /* ---- phase D: reduce, new = res + 0.5*z, write state + output ---- */
    if (tid < CCH) {
      float z = 0.f;
      #pragma unroll
      for (int qq = 0; qq < 16; ++qq) z += zpart[qq][tid];
      z += bm2v;
      float nw = fmaf(0.5f, z, res);
      stN[p*CCH + tid] = nw;
      if (big) ws[WS_OB + (b*TT + t*PT + p)*CCH + tid] = nw;
      else     out[b*CCH*TT + tid*TT + t*PT + p] = nw;
    }
    __syncthreads();   /* drains each wave's vmcnt before the fence/arrival */

    /* ---- per-b 12-block barrier (skip after final step) ---- */
    if (t < NPATCHN-1) {
      if (tid == 0) {
        __hip_atomic_fetch_add(bar, 1, __ATOMIC_RELEASE, __HIP_MEMORY_SCOPE_AGENT);
        int target = 12*(t+1);
        while (__hip_atomic_load(bar, __ATOMIC_RELAXED, __HIP_MEMORY_SCOPE_AGENT) < target)
          __builtin_amdgcn_s_sleep(1);
        __builtin_amdgcn_fence(__ATOMIC_ACQUIRE, "agent");
      }
      __syncthreads();
    }
  }
}

extern "C" void kernel_launch(void* const* d_in, const int* in_sizes, int n_in,
                              void* d_out, int out_size, void* d_ws, size_t ws_size,
                              hipStream_t stream) {
  (void)in_sizes; (void)n_in; (void)out_size;
  const float* x    = (const float*)d_in[0];
  const float* g0   = (const float*)d_in[1];
  const float* b0   = (const float*)d_in[2];
  const float* gg1  = (const float*)d_in[3];
  const float* bb1  = (const float*)d_in[4];
  const float* gg2  = (const float*)d_in[5];
  const float* bb2  = (const float*)d_in[6];
  const float* Wagg = (const float*)d_in[7];
  const float* bagg = (const float*)d_in[8];
  const float* We   = (const float*)d_in[9];
  const float* be   = (const float*)d_in[10];
  const float* Wq   = (const float*)d_in[11];
  const float* bq   = (const float*)d_in[12];
  const float* Wk   = (const float*)d_in[13];
  const float* bk   = (const float*)d_in[14];
  const float* Wv   = (const float*)d_in[15];
  const float* bv   = (const float*)d_in[16];
  const float* Wm1  = (const float*)d_in[17];
  const float* bm1  = (const float*)d_in[18];
  const float* Wm2  = (const float*)d_in[19];
  const float* bm2  = (const float*)d_in[20];
  float* ws  = (float*)d_ws;
  float* out = (float*)d_out;

  int big = (ws_size >= (size_t)WS_END * sizeof(float)) ? 1 : 0;

  hipLaunchKernelGGL(precompute_kernel, dim3(1), dim3(1024), 0, stream,
                     gg1, bb1, gg2, bb2, Wagg, bagg, We, be,
                     Wq, bq, Wk, bk, Wv, bv, Wm1, bm1, Wm2, bm2, ws);
  if (big)
    hipLaunchKernelGGL(pre_transpose, dim3(24, 8, 16), dim3(256), 0, stream, x, g0, b0, ws);

  void* kargs[] = { (void*)&x, (void*)&g0, (void*)&b0, (void*)&ws, (void*)&out, (void*)&big };
  hipLaunchCooperativeKernel(main_kernel, dim3(GRID), dim3(1024), kargs, 0, stream);

  if (big)
    hipLaunchKernelGGL(post_transpose, dim3(24, 8, 16), dim3(256), 0, stream, ws, out);
}